// Round 11
// baseline (348.486 us; speedup 1.0000x reference)
//
#include <hip/hip_runtime.h>

// GMSA r11: conv_in 2-deep prefetch + 3-slot LDS (loads always in flight);
// attn full-row softmax (exact max, no online rescale), P in compact per-wave
// LDS (stride-66 dwords), PV in halves, Vt pad removed via key0&255.
// d_ws: 6 f16 buffers of 2^24 + wf + bias + wo (prep kernel).

typedef _Float16 f16x8 __attribute__((ext_vector_type(8)));
typedef _Float16 f16x4 __attribute__((ext_vector_type(4)));
typedef float    f32x4 __attribute__((ext_vector_type(4)));

__device__ inline float exp2_fast(float x) {
    float r; asm("v_exp_f32 %0, %1" : "=v"(r) : "v"(x)); return r;
}
__device__ inline unsigned pkrtz(float a, float b) {
    return __builtin_bit_cast(unsigned, __builtin_amdgcn_cvt_pkrtz(a, b));
}

// ---- one-shot weight prep -------------------------------------------------
__global__ __launch_bounds__(256) void k_prep(
    const float* __restrict__ w_in, const float* __restrict__ b_in,
    const float* __restrict__ gma, const float* __restrict__ bta,
    const float* __restrict__ mu,  const float* __restrict__ var,
    const float* __restrict__ w_out,
    _Float16* __restrict__ wf, float* __restrict__ bs, _Float16* __restrict__ wo)
{
    const int t = threadIdx.x;
    if (t < 192) {
        const float qs = ((t & 63) < 32) ? 1.2011224087864498f : 1.0f; // sqrt(log2e)
        float iv = gma[t] * rsqrtf(var[t] + 1e-5f);
        float s  = iv * qs;
        bs[t] = (b_in[t]*iv + bta[t] - mu[t]*iv) * qs;
        #pragma unroll
        for (int c4 = 0; c4 < 96; c4 += 4) {
            float4 w = *reinterpret_cast<const float4*>(w_in + t*96 + c4);
            f16x4 h;
            h[0]=(_Float16)(w.x*s); h[1]=(_Float16)(w.y*s);
            h[2]=(_Float16)(w.z*s); h[3]=(_Float16)(w.w*s);
            *reinterpret_cast<f16x4*>(wf + t*96 + c4) = h;
        }
    }
    if (t < 96) {
        #pragma unroll
        for (int c4 = 0; c4 < 96; c4 += 4) {
            float4 w = *reinterpret_cast<const float4*>(w_out + t*96 + c4);
            f16x4 h;
            h[0]=(_Float16)w.x; h[1]=(_Float16)w.y;
            h[2]=(_Float16)w.z; h[3]=(_Float16)w.w;
            *reinterpret_cast<f16x4*>(wo + t*96 + c4) = h;
        }
    }
}

// ---- conv_in: D[192 o][128 px] = wf[o][96] x[96][px] + bs[o] --------------
__global__ __launch_bounds__(256) void k_conv_in(
    const float* __restrict__ x, const _Float16* __restrict__ wf,
    const float* __restrict__ bs,
    _Float16* __restrict__ q0, _Float16* __restrict__ v0,
    _Float16* __restrict__ q1, _Float16* __restrict__ v1,
    _Float16* __restrict__ q2, _Float16* __restrict__ v2)
{
    __shared__ unsigned xs2[3][16*132];   // 3 slots, no reuse: dword=f16 pair
    const int t  = threadIdx.x;
    const int wv = t >> 6, ln = t & 63;
    const int lo = ln & 15, hi = ln >> 4;
    const int oh = wv >> 1, ph = wv & 1;      // wave = 96 o x 64 px

    const int pixbase = blockIdx.x * 128;
    const int b   = pixbase >> 16;
    const int rem = pixbase & 65535;
    const int hh  = rem >> 8;
    const int ww0 = rem & 255;

    const int r0 = t >> 5;                    // pair-row 0..7 (and +8)
    const int q4 = (t & 31) << 2;
    const float* xb = x + (size_t)b*96*65536 + rem + q4;

    float4 A0, A1, A2, A3, B0, B1, B2, B3;

#define CLOAD(Ra,Rb,Rc,Rd,c0) { \
    Ra = *reinterpret_cast<const float4*>(xb + (size_t)(c0 + 2*r0     )*65536); \
    Rb = *reinterpret_cast<const float4*>(xb + (size_t)(c0 + 2*r0 +  1)*65536); \
    Rc = *reinterpret_cast<const float4*>(xb + (size_t)(c0 + 2*r0 + 16)*65536); \
    Rd = *reinterpret_cast<const float4*>(xb + (size_t)(c0 + 2*r0 + 17)*65536); }
#define CWRITE(sl,Ra,Rb,Rc,Rd) { \
    uint4 u0, u1; \
    u0.x = pkrtz(Ra.x, Rb.x); u0.y = pkrtz(Ra.y, Rb.y); \
    u0.z = pkrtz(Ra.z, Rb.z); u0.w = pkrtz(Ra.w, Rb.w); \
    u1.x = pkrtz(Rc.x, Rd.x); u1.y = pkrtz(Rc.y, Rd.y); \
    u1.z = pkrtz(Rc.z, Rd.z); u1.w = pkrtz(Rc.w, Rd.w); \
    *reinterpret_cast<uint4*>(&xs2[sl][ r0     *132 + q4]) = u0; \
    *reinterpret_cast<uint4*>(&xs2[sl][(r0 + 8)*132 + q4]) = u1; }
#define CCOMP(sl, ks) { \
    _Pragma("unroll") for (int cf = 0; cf < 4; ++cf) { \
        const unsigned* bp = &xs2[sl][hi*4*132 + ph*64 + cf*16 + lo]; \
        uint4 u; u.x = bp[0]; u.y = bp[132]; u.z = bp[264]; u.w = bp[396]; \
        f16x8 bfv = __builtin_bit_cast(f16x8, u); \
        _Pragma("unroll") for (int rf = 0; rf < 6; ++rf) \
            acc[rf][cf] = __builtin_amdgcn_mfma_f32_16x16x32_f16( \
                              af[rf][ks], bfv, acc[rf][cf], 0,0,0); } }

    CLOAD(A0, A1, A2, A3, 0);
    CLOAD(B0, B1, B2, B3, 32);     // 2-deep: both prologue chunks in flight

    f16x8 af[6][3];
    const _Float16* wrow0 = wf + (size_t)(oh*96 + lo)*96 + hi*8;
    #pragma unroll
    for (int rf = 0; rf < 6; ++rf)
        #pragma unroll
        for (int ks = 0; ks < 3; ++ks)
            af[rf][ks] = *reinterpret_cast<const f16x8*>(wrow0 + rf*16*96 + ks*32);

    f32x4 acc[6][4];
    #pragma unroll
    for (int rf = 0; rf < 6; ++rf)
        #pragma unroll
        for (int cf = 0; cf < 4; ++cf) acc[rf][cf] = f32x4{0.f,0.f,0.f,0.f};

    CWRITE(0, A0, A1, A2, A3);     // waits chunk0 only (chunk1 stays in flight)
    __syncthreads();
    CLOAD(A0, A1, A2, A3, 64);     // chunk2 issued 2 phases before its use
    CCOMP(0, 0);
    CWRITE(1, B0, B1, B2, B3);     // chunk1 loaded in prologue -> no stall
    __syncthreads();
    CCOMP(1, 1);
    CWRITE(2, A0, A1, A2, A3);     // chunk2 issued ~2 phases ago
    __syncthreads();
    CCOMP(2, 2);

    // windowed scatter (roll folded), px = ph*64 + cf*16 + lo
    int ro[3][4];
    #pragma unroll
    for (int i = 0; i < 3; ++i) {
        const int lg = 2 + i;
        const int ws = 1 << lg;
        const int sft = ws >> 1;
        const int nblk = 256 >> lg;
        int h  = (hh - sft) & 255;
        int nbrow = (b*nblk + (h >> lg))*nblk;
        int hr = h & (ws-1);
        #pragma unroll
        for (int cf = 0; cf < 4; ++cf) {
            int w = (ww0 + ph*64 + cf*16 + lo - sft) & 255;
            ro[i][cf] = (nbrow + (w >> lg))*(ws*ws) + hr*ws + (w & (ws-1));
        }
    }
    #pragma unroll
    for (int rf = 0; rf < 6; ++rf) {
        const int base = oh*96 + rf*16;
        const int o0i  = base + hi*4;
        const int sc   = base >> 6;
        const bool isv = (base & 32) != 0;
        const int c32  = o0i & 31;
        float4 bi = *reinterpret_cast<const float4*>(bs + o0i);
        _Float16* tb = (sc == 0) ? (isv ? v0 : q0)
                     : (sc == 1) ? (isv ? v1 : q1)
                                 : (isv ? v2 : q2);
        #pragma unroll
        for (int cf = 0; cf < 4; ++cf) {
            f16x4 hv;
            hv[0] = (_Float16)(acc[rf][cf][0] + bi.x);
            hv[1] = (_Float16)(acc[rf][cf][1] + bi.y);
            hv[2] = (_Float16)(acc[rf][cf][2] + bi.z);
            hv[3] = (_Float16)(acc[rf][cf][3] + bi.w);
            *reinterpret_cast<f16x4*>(tb + (size_t)ro[sc][cf]*32 + c32) = hv;
        }
    }
#undef CLOAD
#undef CWRITE
#undef CCOMP
}

// ---- attention body: full-row softmax (exact max, no online rescale) ------
template<int GROUP>
__device__ __forceinline__ void attn_body(
    int bid, uint4* Kl, _Float16* Vt, unsigned* P32,
    const _Float16* __restrict__ Q, const _Float16* __restrict__ Ks,
    const _Float16* Vs, _Float16* O)
{
    constexpr int S   = (GROUP==0) ? 16 : (GROUP==1) ? 64 : 256;
    constexpr int GB  = 256 / S;
    constexpr int NFR = S / 16;                    // 16-key frags per rb: 1/4/16
    constexpr int NTL = (S == 16) ? 1 : S / 32;    // 32-key PV tiles: 1/2/8
    constexpr int NH  = (S == 256) ? 2 : 1;        // PV halves
    constexpr int FH  = NFR / NH;                  // frags per half
    constexpr int TPH = NTL / NH;                  // tiles per half

    const int t = threadIdx.x;
    {   // stage K (chunk-scattered) + V^T (stride 264); match_batch folded in
        const int g = t / S, j = t % S;
        const int bq = bid * GB + g;
        int krow, vrow;
        if constexpr (GROUP == 0) {
            krow = (bq >> 2)*64  + (j << 2) + (bq & 3);
            vrow = (bq >> 4)*256 + (j << 4) + (bq & 15);
        } else if constexpr (GROUP == 1) {
            krow = (bq >> 2)*256 + (j << 2) + (bq & 3);
            vrow = ((bq << 2) + (j & 3))*16 + (j >> 2);
        } else {
            krow = ((bq << 4) + (j & 15))*16 + (j >> 4);
            vrow = ((bq << 2) + (j & 3))*64 + (j >> 2);
        }
        const uint4* ks = reinterpret_cast<const uint4*>(Ks + (size_t)krow*32);
        uint4 ka = ks[0], kb = ks[1], kc = ks[2], kd = ks[3];
        Kl[0*256 + t] = ka; Kl[1*256 + t] = kb;
        Kl[2*256 + t] = kc; Kl[3*256 + t] = kd;
        union { uint4 u4[4]; _Float16 h[32]; } vb;
        const uint4* vs = reinterpret_cast<const uint4*>(Vs + (size_t)vrow*32);
        vb.u4[0] = vs[0]; vb.u4[1] = vs[1]; vb.u4[2] = vs[2]; vb.u4[3] = vs[3];
        #pragma unroll
        for (int d = 0; d < 32; ++d) Vt[d*264 + t] = vb.h[d];
    }
    const int wv = t >> 6, ln = t & 63;
    const int lo = ln & 15, hi = ln >> 4;
    unsigned* Pw = P32 + wv*1056;              // per-wave [16 q][66 dw]
    if constexpr (S == 16) {                   // zero key-cols 16..31 (dw 8..15)
        uint2 z; z.x = 0u; z.y = 0u;
        *reinterpret_cast<uint2*>(Pw + (ln >> 2)*66 + 8 + (ln & 3)*2) = z;
    }
    __syncthreads();

    const int rowbase = bid*256 + wv*64;
    f16x8 qf[4];
    #pragma unroll
    for (int rb = 0; rb < 4; ++rb) {
        uint4 qv = *reinterpret_cast<const uint4*>(
            Q + ((size_t)(rowbase + rb*16 + lo))*32 + hi*8);
        qf[rb] = __builtin_bit_cast(f16x8, qv);
    }
    const f32x4 zf = f32x4{0.f,0.f,0.f,0.f};

    #pragma unroll
    for (int rb = 0; rb < 4; ++rb) {
        const int KBr = (S == 16) ? wv*64 + rb*16 : (S == 64) ? wv*64 : 0;
        // QK^T (swapped): sf[f] holds C[key=KBr+f*16+hi*4+r][q=lo]
        f32x4 sf[NFR];
        #pragma unroll
        for (int f = 0; f < NFR; ++f) {
            const int key = KBr + f*16 + lo;
            f16x8 bk = __builtin_bit_cast(f16x8, Kl[hi*256 + key]);
            sf[f] = __builtin_amdgcn_mfma_f32_16x16x32_f16(bk, qf[rb], zf, 0,0,0);
        }
        // exact row max: 4 parallel chains + 2 shfl
        float m0 = sf[0][0], m1 = sf[0][1], m2 = sf[0][2], m3 = sf[0][3];
        #pragma unroll
        for (int f = 1; f < NFR; ++f) {
            m0 = fmaxf(m0, sf[f][0]); m1 = fmaxf(m1, sf[f][1]);
            m2 = fmaxf(m2, sf[f][2]); m3 = fmaxf(m3, sf[f][3]);
        }
        float mx = fmaxf(fmaxf(m0, m1), fmaxf(m2, m3));
        mx = fmaxf(mx, __shfl_xor(mx, 16));
        mx = fmaxf(mx, __shfl_xor(mx, 32));

        float ls0 = 0.f, ls1 = 0.f, ls2 = 0.f, ls3 = 0.f;
        f32x4 ofr0 = zf, ofr1 = zf;
        #pragma unroll
        for (int h = 0; h < NH; ++h) {
            #pragma unroll
            for (int fl = 0; fl < FH; ++fl) {    // exp2 + P write (b64)
                const int f = h*FH + fl;
                float p0 = exp2_fast(sf[f][0] - mx);
                float p1 = exp2_fast(sf[f][1] - mx);
                float p2 = exp2_fast(sf[f][2] - mx);
                float p3 = exp2_fast(sf[f][3] - mx);
                ls0 += p0; ls1 += p1; ls2 += p2; ls3 += p3;
                uint2 w; w.x = pkrtz(p0, p1); w.y = pkrtz(p2, p3);
                *reinterpret_cast<uint2*>(Pw + lo*66 + fl*8 + hi*2) = w;
            }
            #pragma unroll
            for (int tl = 0; tl < TPH; ++tl) {   // PV over this half
                const unsigned* pp = Pw + lo*66 + tl*16 + hi*4;
                uint2 a  = *reinterpret_cast<const uint2*>(pp);
                uint2 b2 = *reinterpret_cast<const uint2*>(pp + 2);
                uint4 pu; pu.x = a.x; pu.y = a.y; pu.z = b2.x; pu.w = b2.y;
                f16x8 pa = __builtin_bit_cast(f16x8, pu);
                const int key0 = (KBr + (h*TPH + tl)*32 + hi*8) & 255;
                f16x8 bv0 = *reinterpret_cast<const f16x8*>(Vt + (     lo)*264 + key0);
                ofr0 = __builtin_amdgcn_mfma_f32_16x16x32_f16(pa, bv0, ofr0, 0,0,0);
                f16x8 bv1 = *reinterpret_cast<const f16x8*>(Vt + (16 + lo)*264 + key0);
                ofr1 = __builtin_amdgcn_mfma_f32_16x16x32_f16(pa, bv1, ofr1, 0,0,0);
            }
        }
        float v = (ls0 + ls1) + (ls2 + ls3);
        v += __shfl_xor(v, 16);
        v += __shfl_xor(v, 32);
        float linv = 1.f / v;
        float l0 = __shfl(linv, hi*4 + 0);
        float l1 = __shfl(linv, hi*4 + 1);
        float l2 = __shfl(linv, hi*4 + 2);
        float l3 = __shfl(linv, hi*4 + 3);
        const int rowb = rowbase + rb*16 + hi*4;
        O[(size_t)(rowb+0)*32      + lo] = (_Float16)(ofr0[0] * l0);
        O[(size_t)(rowb+1)*32      + lo] = (_Float16)(ofr0[1] * l1);
        O[(size_t)(rowb+2)*32      + lo] = (_Float16)(ofr0[2] * l2);
        O[(size_t)(rowb+3)*32      + lo] = (_Float16)(ofr0[3] * l3);
        O[(size_t)(rowb+0)*32 + 16 + lo] = (_Float16)(ofr1[0] * l0);
        O[(size_t)(rowb+1)*32 + 16 + lo] = (_Float16)(ofr1[1] * l1);
        O[(size_t)(rowb+2)*32 + 16 + lo] = (_Float16)(ofr1[2] * l2);
        O[(size_t)(rowb+3)*32 + 16 + lo] = (_Float16)(ofr1[3] * l3);
    }
}

// one kernel, 3 groups: bid<2048 -> G0, <4096 -> G1, else G2 (independent)
__global__ __launch_bounds__(256) void k_attn_all(
    const _Float16* __restrict__ q0, const _Float16* __restrict__ v0,
    const _Float16* __restrict__ q1, const _Float16* __restrict__ v1,
    const _Float16* __restrict__ q2, const _Float16* __restrict__ v2)
{
    __shared__ __align__(16) char smem[16384 + 16896 + 16896];
    uint4*    Kl  = reinterpret_cast<uint4*>(smem);
    _Float16* Vt  = reinterpret_cast<_Float16*>(smem + 16384);
    unsigned* P32 = reinterpret_cast<unsigned*>(smem + 16384 + 16896);
    const int bid = (int)blockIdx.x;
    if (bid < 2048)
        attn_body<0>(bid, Kl, Vt, P32, q0, q1, v2, const_cast<_Float16*>(v2));
    else if (bid < 4096)
        attn_body<1>(bid - 2048, Kl, Vt, P32, q1, q2, v0, const_cast<_Float16*>(v0));
    else
        attn_body<2>(bid - 4096, Kl, Vt, P32, q2, q0, v1, const_cast<_Float16*>(v1));
}

// ---- conv_out (A-frags from pre-folded f16 wo) ----------------------------
__global__ __launch_bounds__(256) void k_conv_out(
    const _Float16* __restrict__ o0, const _Float16* __restrict__ o1,
    const _Float16* __restrict__ o2, const _Float16* __restrict__ wo,
    const float* __restrict__ b_out, float* __restrict__ out)
{
    constexpr int YS = 104;
    __shared__ _Float16 yt[256*YS];
    const int t  = threadIdx.x;
    const int wv = t >> 6, ln = t & 63;
    const int lo = ln & 15, hi = ln >> 4;
    const int bid = (int)blockIdx.x;
    const int swz = (bid & 7)*256 + (bid >> 3);
    const int b = swz >> 8;
    const int h = swz & 255;

    #pragma unroll
    for (int i = 0; i < 3; ++i) {
        const int lg = 2 + i;
        const int ws = 1 << lg;
        const int sft = ws >> 1;
        const int nblk = 256 >> lg;
        int hh = (h - sft) & 255;
        int w  = (t - sft) & 255;
        int nb = (b*nblk + (hh >> lg))*nblk + (w >> lg);
        int roff = nb*(ws*ws) + (hh & (ws-1))*ws + (w & (ws-1));
        const uint4* src = reinterpret_cast<const uint4*>(
            (i==0 ? o0 : i==1 ? o1 : o2) + (size_t)roff*32);
        uint4 r0 = src[0], r1 = src[1], r2 = src[2], r3 = src[3];
        uint4* dst = reinterpret_cast<uint4*>(&yt[t*YS + i*32]);
        dst[0] = r0; dst[1] = r1; dst[2] = r2; dst[3] = r3;
    }

    f16x8 af[6][3];
    #pragma unroll
    for (int rf = 0; rf < 6; ++rf)
        #pragma unroll
        for (int ks = 0; ks < 3; ++ks)
            af[rf][ks] = *reinterpret_cast<const f16x8*>(
                wo + (rf*16 + lo)*96 + ks*32 + hi*8);
    __syncthreads();

    f32x4 acc[6][4];
    #pragma unroll
    for (int rf = 0; rf < 6; ++rf)
        #pragma unroll
        for (int cf = 0; cf < 4; ++cf) acc[rf][cf] = f32x4{0.f,0.f,0.f,0.f};

    #pragma unroll
    for (int cf = 0; cf < 4; ++cf) {
        const int px = wv*64 + cf*16 + lo;
        #pragma unroll
        for (int ks = 0; ks < 3; ++ks) {
            f16x8 bfv = *reinterpret_cast<const f16x8*>(&yt[px*YS + ks*32 + hi*8]);
            #pragma unroll
            for (int rf = 0; rf < 6; ++rf)
                acc[rf][cf] = __builtin_amdgcn_mfma_f32_16x16x32_f16(
                                  af[rf][ks], bfv, acc[rf][cf], 0,0,0);
        }
    }

    const size_t obase = (size_t)b*96*65536 + (size_t)h*256;
    #pragma unroll
    for (int rf = 0; rf < 6; ++rf) {
        const int oo = rf*16 + hi*4;
        float4 bi = *reinterpret_cast<const float4*>(b_out + oo);
        #pragma unroll
        for (int cf = 0; cf < 4; ++cf) {
            const int px = wv*64 + cf*16 + lo;
            out[obase + (size_t)(oo+0)*65536 + px] = acc[rf][cf][0] + bi.x;
            out[obase + (size_t)(oo+1)*65536 + px] = acc[rf][cf][1] + bi.y;
            out[obase + (size_t)(oo+2)*65536 + px] = acc[rf][cf][2] + bi.z;
            out[obase + (size_t)(oo+3)*65536 + px] = acc[rf][cf][3] + bi.w;
        }
    }
}

extern "C" void kernel_launch(void* const* d_in, const int* in_sizes, int n_in,
                              void* d_out, int out_size, void* d_ws, size_t ws_size,
                              hipStream_t stream)
{
    const float* x     = (const float*)d_in[0];
    const float* w_in  = (const float*)d_in[1];
    const float* b_in  = (const float*)d_in[2];
    const float* gma   = (const float*)d_in[3];
    const float* bta   = (const float*)d_in[4];
    const float* mu    = (const float*)d_in[5];
    const float* var   = (const float*)d_in[6];
    const float* w_out = (const float*)d_in[7];
    const float* b_out = (const float*)d_in[8];
    float* out = (float*)d_out;

    _Float16* W = (_Float16*)d_ws;
    const size_t M = 16777216;
    _Float16 *q0 = W,       *v0 = W +   M, *q1 = W + 2*M,
             *v1 = W + 3*M, *q2 = W + 4*M, *v2 = W + 5*M;
    _Float16* wf = W + 6*M;
    float*    bs = (float*)(W + 6*M + 18432);
    _Float16* wo = W + 6*M + 18432 + 384;

    k_prep<<<1, 256, 0, stream>>>(w_in, b_in, gma, bta, mu, var, w_out, wf, bs, wo);
    k_conv_in<<<4096, 256, 0, stream>>>(x, wf, bs, q0, v0, q1, v1, q2, v2);
    k_attn_all<<<6144, 256, 0, stream>>>(q0, v0, q1, v1, q2, v2);
    k_conv_out<<<2048, 256, 0, stream>>>(v2, v0, v1, wo, b_out, out);
}

// Round 12
// 290.456 us; speedup vs baseline: 1.1998x; 1.1998x over previous
//
#include <hip/hip_runtime.h>

// GMSA r12: attn + conv_out reverted to r10 (proven). conv_in: 4 tiles/block
// (grid 1024), 12-phase rolling pipeline, depth-2 loads, 3 LDS slots -> one
// prologue per block instead of four. d_ws: 6 f16 bufs 2^24 + wf + bias + wo.

typedef _Float16 f16x8 __attribute__((ext_vector_type(8)));
typedef _Float16 f16x4 __attribute__((ext_vector_type(4)));
typedef float    f32x4 __attribute__((ext_vector_type(4)));

__device__ inline float exp2_fast(float x) {
    float r; asm("v_exp_f32 %0, %1" : "=v"(r) : "v"(x)); return r;
}
__device__ inline unsigned pkrtz(float a, float b) {
    return __builtin_bit_cast(unsigned, __builtin_amdgcn_cvt_pkrtz(a, b));
}

// ---- one-shot weight prep -------------------------------------------------
__global__ __launch_bounds__(256) void k_prep(
    const float* __restrict__ w_in, const float* __restrict__ b_in,
    const float* __restrict__ gma, const float* __restrict__ bta,
    const float* __restrict__ mu,  const float* __restrict__ var,
    const float* __restrict__ w_out,
    _Float16* __restrict__ wf, float* __restrict__ bs, _Float16* __restrict__ wo)
{
    const int t = threadIdx.x;
    if (t < 192) {
        const float qs = ((t & 63) < 32) ? 1.2011224087864498f : 1.0f; // sqrt(log2e)
        float iv = gma[t] * rsqrtf(var[t] + 1e-5f);
        float s  = iv * qs;
        bs[t] = (b_in[t]*iv + bta[t] - mu[t]*iv) * qs;
        #pragma unroll
        for (int c4 = 0; c4 < 96; c4 += 4) {
            float4 w = *reinterpret_cast<const float4*>(w_in + t*96 + c4);
            f16x4 h;
            h[0]=(_Float16)(w.x*s); h[1]=(_Float16)(w.y*s);
            h[2]=(_Float16)(w.z*s); h[3]=(_Float16)(w.w*s);
            *reinterpret_cast<f16x4*>(wf + t*96 + c4) = h;
        }
    }
    if (t < 96) {
        #pragma unroll
        for (int c4 = 0; c4 < 96; c4 += 4) {
            float4 w = *reinterpret_cast<const float4*>(w_out + t*96 + c4);
            f16x4 h;
            h[0]=(_Float16)w.x; h[1]=(_Float16)w.y;
            h[2]=(_Float16)w.z; h[3]=(_Float16)w.w;
            *reinterpret_cast<f16x4*>(wo + t*96 + c4) = h;
        }
    }
}

// ---- conv_in: 4 tiles of 128 px per block, 12-phase rolling pipeline ------
__global__ __launch_bounds__(256) void k_conv_in(
    const float* __restrict__ x, const _Float16* __restrict__ wf,
    const float* __restrict__ bs,
    _Float16* __restrict__ q0, _Float16* __restrict__ v0,
    _Float16* __restrict__ q1, _Float16* __restrict__ v1,
    _Float16* __restrict__ q2, _Float16* __restrict__ v2)
{
    __shared__ unsigned xs2[3][16*132];   // 3 slots; dword = f16 pair per px
    const int t  = threadIdx.x;
    const int wv = t >> 6, ln = t & 63;
    const int lo = ln & 15, hi = ln >> 4;
    const int oh = wv >> 1, ph = wv & 1;      // wave = 96 o x 64 px

    const int base_px = blockIdx.x * 512;     // 4 tiles x 128 px; never crosses b
    const int b    = base_px >> 16;
    const int rem0 = base_px & 65535;

    const int r0 = t >> 5;                    // pair-row 0..7 (and +8)
    const int q4 = (t & 31) << 2;
    const float* xbb = x + (size_t)b*96*65536 + rem0 + q4;

    float4 RS[2][4];                          // 2 load sets (depth-2)

    // chunk cch (0..11): tile T=cch/3 (pixel offset T*128), channels (cch%3)*32
#define CLOAD(st, cch) { \
    const float* xp_ = xbb + ((cch)/3)*128 + (size_t)(((cch)%3)*32 + 2*r0)*65536; \
    RS[st][0] = *reinterpret_cast<const float4*>(xp_); \
    RS[st][1] = *reinterpret_cast<const float4*>(xp_ + (size_t)   65536); \
    RS[st][2] = *reinterpret_cast<const float4*>(xp_ + (size_t)16*65536); \
    RS[st][3] = *reinterpret_cast<const float4*>(xp_ + (size_t)17*65536); }
#define CWRITE(sl, st) { \
    uint4 u0, u1; \
    u0.x = pkrtz(RS[st][0].x, RS[st][1].x); u0.y = pkrtz(RS[st][0].y, RS[st][1].y); \
    u0.z = pkrtz(RS[st][0].z, RS[st][1].z); u0.w = pkrtz(RS[st][0].w, RS[st][1].w); \
    u1.x = pkrtz(RS[st][2].x, RS[st][3].x); u1.y = pkrtz(RS[st][2].y, RS[st][3].y); \
    u1.z = pkrtz(RS[st][2].z, RS[st][3].z); u1.w = pkrtz(RS[st][2].w, RS[st][3].w); \
    *reinterpret_cast<uint4*>(&xs2[sl][ r0     *132 + q4]) = u0; \
    *reinterpret_cast<uint4*>(&xs2[sl][(r0 + 8)*132 + q4]) = u1; }
#define CCOMP(sl, ks) { \
    _Pragma("unroll") for (int cf = 0; cf < 4; ++cf) { \
        const unsigned* bp = &xs2[sl][hi*4*132 + ph*64 + cf*16 + lo]; \
        uint4 u; u.x = bp[0]; u.y = bp[132]; u.z = bp[264]; u.w = bp[396]; \
        f16x8 bfv = __builtin_bit_cast(f16x8, u); \
        _Pragma("unroll") for (int rf = 0; rf < 6; ++rf) \
            acc[rf][cf] = __builtin_amdgcn_mfma_f32_16x16x32_f16( \
                              af[rf][ks], bfv, acc[rf][cf], 0,0,0); } }

    CLOAD(0, 0);
    CLOAD(1, 1);

    f16x8 af[6][3];
    const _Float16* wrow0 = wf + (size_t)(oh*96 + lo)*96 + hi*8;
    #pragma unroll
    for (int rf = 0; rf < 6; ++rf)
        #pragma unroll
        for (int ks = 0; ks < 3; ++ks)
            af[rf][ks] = *reinterpret_cast<const f16x8*>(wrow0 + rf*16*96 + ks*32);

    f32x4 acc[6][4];
    #pragma unroll
    for (int rf = 0; rf < 6; ++rf)
        #pragma unroll
        for (int cf = 0; cf < 4; ++cf) acc[rf][cf] = f32x4{0.f,0.f,0.f,0.f};

    CWRITE(0, 0);
    __syncthreads();

    #pragma unroll
    for (int c = 0; c < 12; ++c) {
        CCOMP(c % 3, c % 3);
        if ((c % 3) == 2) {
            // ---- epilogue for tile T = c/3: windowed scatter + acc reset
            const int T   = c / 3;
            const int rem = rem0 + T*128;
            const int hh  = rem >> 8;
            const int ww0 = rem & 255;
            int ro[3][4];
            #pragma unroll
            for (int i = 0; i < 3; ++i) {
                const int lg = 2 + i;
                const int ws = 1 << lg;
                const int sft = ws >> 1;
                const int nblk = 256 >> lg;
                int h  = (hh - sft) & 255;
                int nbrow = (b*nblk + (h >> lg))*nblk;
                int hr = h & (ws-1);
                #pragma unroll
                for (int cf = 0; cf < 4; ++cf) {
                    int w = (ww0 + ph*64 + cf*16 + lo - sft) & 255;
                    ro[i][cf] = (nbrow + (w >> lg))*(ws*ws) + hr*ws + (w & (ws-1));
                }
            }
            #pragma unroll
            for (int rf = 0; rf < 6; ++rf) {
                const int base = oh*96 + rf*16;
                const int o0i  = base + hi*4;
                const int sc   = base >> 6;
                const bool isv = (base & 32) != 0;
                const int c32  = o0i & 31;
                float4 bi = *reinterpret_cast<const float4*>(bs + o0i);
                _Float16* tb = (sc == 0) ? (isv ? v0 : q0)
                             : (sc == 1) ? (isv ? v1 : q1)
                                         : (isv ? v2 : q2);
                #pragma unroll
                for (int cf = 0; cf < 4; ++cf) {
                    f16x4 hv;
                    hv[0] = (_Float16)(acc[rf][cf][0] + bi.x);
                    hv[1] = (_Float16)(acc[rf][cf][1] + bi.y);
                    hv[2] = (_Float16)(acc[rf][cf][2] + bi.z);
                    hv[3] = (_Float16)(acc[rf][cf][3] + bi.w);
                    *reinterpret_cast<f16x4*>(tb + (size_t)ro[sc][cf]*32 + c32) = hv;
                    acc[rf][cf] = f32x4{0.f,0.f,0.f,0.f};
                }
            }
        }
        if (c + 1 < 12) CWRITE((c + 1) % 3, (c + 1) & 1);
        if (c + 2 < 12) CLOAD(c & 1, c + 2);
        __syncthreads();
    }
#undef CLOAD
#undef CWRITE
#undef CCOMP
}

// ---- Flash attention body (r10 verbatim: online softmax, swapped QK^T) ----
template<int GROUP>
__device__ __forceinline__ void attn_body(
    int bid, uint4* Kl, _Float16* Vt, _Float16* Pl,
    const _Float16* __restrict__ Q, const _Float16* __restrict__ Ks,
    const _Float16* Vs, _Float16* O)
{
    constexpr int S   = (GROUP==0) ? 16 : (GROUP==1) ? 64 : 256;
    constexpr int GB  = 256 / S;
    constexpr int KT  = (S < 32) ? 16 : 32;
    constexpr int NT  = S / KT;
    constexpr int CBS = KT / 16;

    const int t = threadIdx.x;
    {
        const int g = t / S, j = t % S;
        const int bq = bid * GB + g;
        int krow, vrow;
        if constexpr (GROUP == 0) {
            krow = (bq >> 2)*64  + (j << 2) + (bq & 3);
            vrow = (bq >> 4)*256 + (j << 4) + (bq & 15);
        } else if constexpr (GROUP == 1) {
            krow = (bq >> 2)*256 + (j << 2) + (bq & 3);
            vrow = ((bq << 2) + (j & 3))*16 + (j >> 2);
        } else {
            krow = ((bq << 4) + (j & 15))*16 + (j >> 4);
            vrow = ((bq << 2) + (j & 3))*64 + (j >> 2);
        }
        const uint4* ks = reinterpret_cast<const uint4*>(Ks + (size_t)krow*32);
        uint4 ka = ks[0], kb = ks[1], kc = ks[2], kd = ks[3];
        Kl[0*256 + t] = ka; Kl[1*256 + t] = kb;
        Kl[2*256 + t] = kc; Kl[3*256 + t] = kd;
        union { uint4 u4[4]; _Float16 h[32]; } vb;
        const uint4* vs = reinterpret_cast<const uint4*>(Vs + (size_t)vrow*32);
        vb.u4[0] = vs[0]; vb.u4[1] = vs[1]; vb.u4[2] = vs[2]; vb.u4[3] = vs[3];
        #pragma unroll
        for (int d = 0; d < 32; ++d) Vt[d*264 + t] = vb.h[d];
        Vt[(t >> 3)*264 + 256 + (t & 7)] = (_Float16)0.f;
        if (t < 8) Vt[32*264 + t] = (_Float16)0.f;
    }
    const int wv = t >> 6, ln = t & 63;
    const int lo = ln & 15, hi = ln >> 4;
    _Float16* Pw = Pl + wv*(64*40);
    if constexpr (S == 16) {
        uint* pw32 = reinterpret_cast<uint*>(Pw);
        #pragma unroll
        for (int k2 = 0; k2 < 8; ++k2) {
            int idx = ln + k2*64;
            pw32[(idx >> 3)*20 + 8 + (idx & 7)] = 0u;
        }
    }
    __syncthreads();

    const int rowbase = bid*256 + wv*64;
    f16x8 qf[4];
    #pragma unroll
    for (int rb = 0; rb < 4; ++rb) {
        uint4 qv = *reinterpret_cast<const uint4*>(
            Q + ((size_t)(rowbase + rb*16 + lo))*32 + hi*8);
        qf[rb] = __builtin_bit_cast(f16x8, qv);
    }

    f32x4 ofr[4][2];
    float m[4], ls[4];
    #pragma unroll
    for (int rb = 0; rb < 4; ++rb) {
        m[rb] = -1e30f; ls[rb] = 0.f;
        ofr[rb][0] = f32x4{0.f,0.f,0.f,0.f};
        ofr[rb][1] = f32x4{0.f,0.f,0.f,0.f};
    }
    const f32x4 zf = f32x4{0.f,0.f,0.f,0.f};

    for (int tt = 0; tt < NT; ++tt) {
        f32x4 sf[4][CBS];
        if constexpr (S == 16) {
            #pragma unroll
            for (int rb = 0; rb < 4; ++rb) {
                int key = wv*64 + rb*16 + lo;
                f16x8 bk = __builtin_bit_cast(f16x8, Kl[hi*256 + key]);
                sf[rb][0] = __builtin_amdgcn_mfma_f32_16x16x32_f16(bk, qf[rb], zf, 0,0,0);
            }
        } else {
            f16x8 bk[CBS];
            const int wb = (S == 64) ? wv*64 : 0;
            #pragma unroll
            for (int cb = 0; cb < CBS; ++cb) {
                int key = wb + tt*KT + cb*16 + lo;
                bk[cb] = __builtin_bit_cast(f16x8, Kl[hi*256 + key]);
            }
            #pragma unroll
            for (int rb = 0; rb < 4; ++rb)
                #pragma unroll
                for (int cb = 0; cb < CBS; ++cb)
                    sf[rb][cb] = __builtin_amdgcn_mfma_f32_16x16x32_f16(bk[cb], qf[rb], zf, 0,0,0);
        }

        #pragma unroll
        for (int rb = 0; rb < 4; ++rb) {
            float tm = sf[rb][0][0];
            #pragma unroll
            for (int cb = 0; cb < CBS; ++cb)
                #pragma unroll
                for (int r = 0; r < 4; ++r)
                    if (cb | r) tm = fmaxf(tm, sf[rb][cb][r]);
            tm = fmaxf(tm, __shfl_xor(tm, 16));
            tm = fmaxf(tm, __shfl_xor(tm, 32));
            float mn = fmaxf(m[rb], tm);
            float sc = exp2_fast(m[rb] - mn);
            m[rb] = mn;
            float ps = 0.f;
            #pragma unroll
            for (int cb = 0; cb < CBS; ++cb) {
                float p0 = exp2_fast(sf[rb][cb][0] - mn);
                float p1 = exp2_fast(sf[rb][cb][1] - mn);
                float p2 = exp2_fast(sf[rb][cb][2] - mn);
                float p3 = exp2_fast(sf[rb][cb][3] - mn);
                ps += (p0+p1)+(p2+p3);
                unsigned w01 = pkrtz(p0, p1);
                unsigned w23 = pkrtz(p2, p3);
                _Float16* pp = Pw + (rb*16 + lo)*40 + cb*16 + hi*4;
                *reinterpret_cast<unsigned*>(pp)     = w01;
                *reinterpret_cast<unsigned*>(pp + 2) = w23;
            }
            ls[rb] = ls[rb]*sc + ps;
            float s0 = __shfl(sc, hi*4 + 0);
            float s1 = __shfl(sc, hi*4 + 1);
            float s2 = __shfl(sc, hi*4 + 2);
            float s3 = __shfl(sc, hi*4 + 3);
            ofr[rb][0][0]*=s0; ofr[rb][0][1]*=s1; ofr[rb][0][2]*=s2; ofr[rb][0][3]*=s3;
            ofr[rb][1][0]*=s0; ofr[rb][1][1]*=s1; ofr[rb][1][2]*=s2; ofr[rb][1][3]*=s3;
        }

        #pragma unroll
        for (int rb = 0; rb < 4; ++rb) {
            f16x8 pa = *reinterpret_cast<const f16x8*>(Pw + (rb*16 + lo)*40 + hi*8);
            const int wb = (S == 16) ? wv*64 + rb*16 : (S == 64) ? wv*64 : 0;
            const int key0 = wb + tt*KT + hi*8;
            #pragma unroll
            for (int dcb = 0; dcb < 2; ++dcb) {
                f16x8 bv = *reinterpret_cast<const f16x8*>(Vt + (dcb*16 + lo)*264 + key0);
                ofr[rb][dcb] = __builtin_amdgcn_mfma_f32_16x16x32_f16(pa, bv, ofr[rb][dcb], 0,0,0);
            }
        }
    }

    #pragma unroll
    for (int rb = 0; rb < 4; ++rb) {
        float v = ls[rb];
        v += __shfl_xor(v, 16);
        v += __shfl_xor(v, 32);
        float linv = 1.f / v;
        float l0 = __shfl(linv, hi*4 + 0);
        float l1 = __shfl(linv, hi*4 + 1);
        float l2 = __shfl(linv, hi*4 + 2);
        float l3 = __shfl(linv, hi*4 + 3);
        #pragma unroll
        for (int dcb = 0; dcb < 2; ++dcb) {
            float lr[4] = {l0, l1, l2, l3};
            #pragma unroll
            for (int r = 0; r < 4; ++r) {
                float ov = ofr[rb][dcb][r] * lr[r];
                int row = rowbase + rb*16 + hi*4 + r;
                O[(size_t)row*32 + dcb*16 + lo] = (_Float16)ov;
            }
        }
    }
}

__global__ __launch_bounds__(256) void k_attn_all(
    const _Float16* __restrict__ q0, const _Float16* __restrict__ v0,
    const _Float16* __restrict__ q1, const _Float16* __restrict__ v1,
    const _Float16* __restrict__ q2, const _Float16* __restrict__ v2)
{
    __shared__ __align__(16) char smem[16384 + 16912 + 20480];
    uint4*    Kl = reinterpret_cast<uint4*>(smem);
    _Float16* Vt = reinterpret_cast<_Float16*>(smem + 16384);
    _Float16* Pl = reinterpret_cast<_Float16*>(smem + 16384 + 16912);
    const int bid = (int)blockIdx.x;
    if (bid < 2048)
        attn_body<0>(bid, Kl, Vt, Pl, q0, q1, v2, const_cast<_Float16*>(v2));
    else if (bid < 4096)
        attn_body<1>(bid - 2048, Kl, Vt, Pl, q1, q2, v0, const_cast<_Float16*>(v0));
    else
        attn_body<2>(bid - 4096, Kl, Vt, Pl, q2, q0, v1, const_cast<_Float16*>(v1));
}

// ---- conv_out (r10 verbatim) ----------------------------------------------
__global__ __launch_bounds__(256) void k_conv_out(
    const _Float16* __restrict__ o0, const _Float16* __restrict__ o1,
    const _Float16* __restrict__ o2, const _Float16* __restrict__ wo,
    const float* __restrict__ b_out, float* __restrict__ out)
{
    constexpr int YS = 104;
    __shared__ _Float16 yt[256*YS];
    const int t  = threadIdx.x;
    const int wv = t >> 6, ln = t & 63;
    const int lo = ln & 15, hi = ln >> 4;
    const int bid = (int)blockIdx.x;
    const int swz = (bid & 7)*256 + (bid >> 3);
    const int b = swz >> 8;
    const int h = swz & 255;

    #pragma unroll
    for (int i = 0; i < 3; ++i) {
        const int lg = 2 + i;
        const int ws = 1 << lg;
        const int sft = ws >> 1;
        const int nblk = 256 >> lg;
        int hh = (h - sft) & 255;
        int w  = (t - sft) & 255;
        int nb = (b*nblk + (hh >> lg))*nblk + (w >> lg);
        int roff = nb*(ws*ws) + (hh & (ws-1))*ws + (w & (ws-1));
        const uint4* src = reinterpret_cast<const uint4*>(
            (i==0 ? o0 : i==1 ? o1 : o2) + (size_t)roff*32);
        uint4 r0 = src[0], r1 = src[1], r2 = src[2], r3 = src[3];
        uint4* dst = reinterpret_cast<uint4*>(&yt[t*YS + i*32]);
        dst[0] = r0; dst[1] = r1; dst[2] = r2; dst[3] = r3;
    }

    f16x8 af[6][3];
    #pragma unroll
    for (int rf = 0; rf < 6; ++rf)
        #pragma unroll
        for (int ks = 0; ks < 3; ++ks)
            af[rf][ks] = *reinterpret_cast<const f16x8*>(
                wo + (rf*16 + lo)*96 + ks*32 + hi*8);
    __syncthreads();

    f32x4 acc[6][4];
    #pragma unroll
    for (int rf = 0; rf < 6; ++rf)
        #pragma unroll
        for (int cf = 0; cf < 4; ++cf) acc[rf][cf] = f32x4{0.f,0.f,0.f,0.f};

    #pragma unroll
    for (int cf = 0; cf < 4; ++cf) {
        const int px = wv*64 + cf*16 + lo;
        #pragma unroll
        for (int ks = 0; ks < 3; ++ks) {
            f16x8 bfv = *reinterpret_cast<const f16x8*>(&yt[px*YS + ks*32 + hi*8]);
            #pragma unroll
            for (int rf = 0; rf < 6; ++rf)
                acc[rf][cf] = __builtin_amdgcn_mfma_f32_16x16x32_f16(
                                  af[rf][ks], bfv, acc[rf][cf], 0,0,0);
        }
    }

    const size_t obase = (size_t)b*96*65536 + (size_t)h*256;
    #pragma unroll
    for (int rf = 0; rf < 6; ++rf) {
        const int oo = rf*16 + hi*4;
        float4 bi = *reinterpret_cast<const float4*>(b_out + oo);
        #pragma unroll
        for (int cf = 0; cf < 4; ++cf) {
            const int px = wv*64 + cf*16 + lo;
            out[obase + (size_t)(oo+0)*65536 + px] = acc[rf][cf][0] + bi.x;
            out[obase + (size_t)(oo+1)*65536 + px] = acc[rf][cf][1] + bi.y;
            out[obase + (size_t)(oo+2)*65536 + px] = acc[rf][cf][2] + bi.z;
            out[obase + (size_t)(oo+3)*65536 + px] = acc[rf][cf][3] + bi.w;
        }
    }
}

extern "C" void kernel_launch(void* const* d_in, const int* in_sizes, int n_in,
                              void* d_out, int out_size, void* d_ws, size_t ws_size,
                              hipStream_t stream)
{
    const float* x     = (const float*)d_in[0];
    const float* w_in  = (const float*)d_in[1];
    const float* b_in  = (const float*)d_in[2];
    const float* gma   = (const float*)d_in[3];
    const float* bta   = (const float*)d_in[4];
    const float* mu    = (const float*)d_in[5];
    const float* var   = (const float*)d_in[6];
    const float* w_out = (const float*)d_in[7];
    const float* b_out = (const float*)d_in[8];
    float* out = (float*)d_out;

    _Float16* W = (_Float16*)d_ws;
    const size_t M = 16777216;
    _Float16 *q0 = W,       *v0 = W +   M, *q1 = W + 2*M,
             *v1 = W + 3*M, *q2 = W + 4*M, *v2 = W + 5*M;
    _Float16* wf = W + 6*M;
    float*    bs = (float*)(W + 6*M + 18432);
    _Float16* wo = W + 6*M + 18432 + 384;

    k_prep<<<1, 256, 0, stream>>>(w_in, b_in, gma, bta, mu, var, w_out, wf, bs, wo);
    k_conv_in<<<1024, 256, 0, stream>>>(x, wf, bs, q0, v0, q1, v1, q2, v2);
    k_attn_all<<<6144, 256, 0, stream>>>(q0, v0, q1, v1, q2, v2);
    k_conv_out<<<2048, 256, 0, stream>>>(v2, v0, v1, wo, b_out, out);
}

// Round 13
// 268.609 us; speedup vs baseline: 1.2974x; 1.0813x over previous
//
#include <hip/hip_runtime.h>

// GMSA r13: conv_in reverted to r10-exact (proven 118us). attn: per-rb fused
// P-write+PV -> Pw shrinks [64][40]->[16][40] per wave; LDS 54.3->38.4KB ->
// 4 blocks/CU (was 2, LDS-limited). conv_out r10. d_ws: 6 bufs + wf/bias/wo.

typedef _Float16 f16x8 __attribute__((ext_vector_type(8)));
typedef _Float16 f16x4 __attribute__((ext_vector_type(4)));
typedef float    f32x4 __attribute__((ext_vector_type(4)));

__device__ inline float exp2_fast(float x) {
    float r; asm("v_exp_f32 %0, %1" : "=v"(r) : "v"(x)); return r;
}
__device__ inline unsigned pkrtz(float a, float b) {
    return __builtin_bit_cast(unsigned, __builtin_amdgcn_cvt_pkrtz(a, b));
}

// ---- one-shot weight prep -------------------------------------------------
__global__ __launch_bounds__(256) void k_prep(
    const float* __restrict__ w_in, const float* __restrict__ b_in,
    const float* __restrict__ gma, const float* __restrict__ bta,
    const float* __restrict__ mu,  const float* __restrict__ var,
    const float* __restrict__ w_out,
    _Float16* __restrict__ wf, float* __restrict__ bs, _Float16* __restrict__ wo)
{
    const int t = threadIdx.x;
    if (t < 192) {
        const float qs = ((t & 63) < 32) ? 1.2011224087864498f : 1.0f; // sqrt(log2e)
        float iv = gma[t] * rsqrtf(var[t] + 1e-5f);
        float s  = iv * qs;
        bs[t] = (b_in[t]*iv + bta[t] - mu[t]*iv) * qs;
        #pragma unroll
        for (int c4 = 0; c4 < 96; c4 += 4) {
            float4 w = *reinterpret_cast<const float4*>(w_in + t*96 + c4);
            f16x4 h;
            h[0]=(_Float16)(w.x*s); h[1]=(_Float16)(w.y*s);
            h[2]=(_Float16)(w.z*s); h[3]=(_Float16)(w.w*s);
            *reinterpret_cast<f16x4*>(wf + t*96 + c4) = h;
        }
    }
    if (t < 96) {
        #pragma unroll
        for (int c4 = 0; c4 < 96; c4 += 4) {
            float4 w = *reinterpret_cast<const float4*>(w_out + t*96 + c4);
            f16x4 h;
            h[0]=(_Float16)w.x; h[1]=(_Float16)w.y;
            h[2]=(_Float16)w.z; h[3]=(_Float16)w.w;
            *reinterpret_cast<f16x4*>(wo + t*96 + c4) = h;
        }
    }
}

// ---- conv_in (r10 exact): D[192 o][128 px] = wf[o][96] x[96][px] + bs[o] --
__global__ __launch_bounds__(256) void k_conv_in(
    const float* __restrict__ x, const _Float16* __restrict__ wf,
    const float* __restrict__ bs,
    _Float16* __restrict__ q0, _Float16* __restrict__ v0,
    _Float16* __restrict__ q1, _Float16* __restrict__ v1,
    _Float16* __restrict__ q2, _Float16* __restrict__ v2)
{
    __shared__ unsigned xs2[2][16*132];   // dword = f16 pair (2c2, 2c2+1) per px
    const int t  = threadIdx.x;
    const int wv = t >> 6, ln = t & 63;
    const int lo = ln & 15, hi = ln >> 4;
    const int oh = wv >> 1, ph = wv & 1;      // wave = 96 o x 64 px

    const int pixbase = blockIdx.x * 128;
    const int b   = pixbase >> 16;
    const int rem = pixbase & 65535;
    const int hh  = rem >> 8;
    const int ww0 = rem & 255;

    const int r0 = t >> 5;                    // pair-row 0..7 (and +8)
    const int q4 = (t & 31) << 2;
    const float* xb = x + (size_t)b*96*65536 + rem + q4;

    float4 L0, L1, L2, L3;

#define CLOAD(c0) { \
    L0 = *reinterpret_cast<const float4*>(xb + (size_t)(c0 + 2*r0     )*65536); \
    L1 = *reinterpret_cast<const float4*>(xb + (size_t)(c0 + 2*r0 +  1)*65536); \
    L2 = *reinterpret_cast<const float4*>(xb + (size_t)(c0 + 2*r0 + 16)*65536); \
    L3 = *reinterpret_cast<const float4*>(xb + (size_t)(c0 + 2*r0 + 17)*65536); }
#define CWRITE(bf) { \
    uint4 u0, u1; \
    u0.x = pkrtz(L0.x, L1.x); u0.y = pkrtz(L0.y, L1.y); \
    u0.z = pkrtz(L0.z, L1.z); u0.w = pkrtz(L0.w, L1.w); \
    u1.x = pkrtz(L2.x, L3.x); u1.y = pkrtz(L2.y, L3.y); \
    u1.z = pkrtz(L2.z, L3.z); u1.w = pkrtz(L2.w, L3.w); \
    *reinterpret_cast<uint4*>(&xs2[bf][ r0     *132 + q4]) = u0; \
    *reinterpret_cast<uint4*>(&xs2[bf][(r0 + 8)*132 + q4]) = u1; }
#define CCOMP(bf, ks) { \
    _Pragma("unroll") for (int cf = 0; cf < 4; ++cf) { \
        const unsigned* bp = &xs2[bf][hi*4*132 + ph*64 + cf*16 + lo]; \
        uint4 u; u.x = bp[0]; u.y = bp[132]; u.z = bp[264]; u.w = bp[396]; \
        f16x8 bfv = __builtin_bit_cast(f16x8, u); \
        _Pragma("unroll") for (int rf = 0; rf < 6; ++rf) \
            acc[rf][cf] = __builtin_amdgcn_mfma_f32_16x16x32_f16( \
                              af[rf][ks], bfv, acc[rf][cf], 0,0,0); } }

    CLOAD(0);

    f16x8 af[6][3];
    const _Float16* wrow0 = wf + (size_t)(oh*96 + lo)*96 + hi*8;
    #pragma unroll
    for (int rf = 0; rf < 6; ++rf)
        #pragma unroll
        for (int ks = 0; ks < 3; ++ks)
            af[rf][ks] = *reinterpret_cast<const f16x8*>(wrow0 + rf*16*96 + ks*32);

    f32x4 acc[6][4];
    #pragma unroll
    for (int rf = 0; rf < 6; ++rf)
        #pragma unroll
        for (int cf = 0; cf < 4; ++cf) acc[rf][cf] = f32x4{0.f,0.f,0.f,0.f};

    CWRITE(0);
    __syncthreads();
    CLOAD(32);                 // chunk1 in flight under COMPUTE(0)
    CCOMP(0, 0);
    CWRITE(1);
    __syncthreads();
    CLOAD(64);                 // chunk2 in flight under COMPUTE(1)
    CCOMP(1, 1);
    CWRITE(0);                 // safe: all waves left chunk0 at last barrier
    __syncthreads();
    CCOMP(0, 2);

    int ro[3][4];
    #pragma unroll
    for (int i = 0; i < 3; ++i) {
        const int lg = 2 + i;
        const int ws = 1 << lg;
        const int sft = ws >> 1;
        const int nblk = 256 >> lg;
        int h  = (hh - sft) & 255;
        int nbrow = (b*nblk + (h >> lg))*nblk;
        int hr = h & (ws-1);
        #pragma unroll
        for (int cf = 0; cf < 4; ++cf) {
            int w = (ww0 + ph*64 + cf*16 + lo - sft) & 255;
            ro[i][cf] = (nbrow + (w >> lg))*(ws*ws) + hr*ws + (w & (ws-1));
        }
    }
    #pragma unroll
    for (int rf = 0; rf < 6; ++rf) {
        const int base = oh*96 + rf*16;
        const int o0i  = base + hi*4;
        const int sc   = base >> 6;
        const bool isv = (base & 32) != 0;
        const int c32  = o0i & 31;
        float4 bi = *reinterpret_cast<const float4*>(bs + o0i);
        _Float16* tb = (sc == 0) ? (isv ? v0 : q0)
                     : (sc == 1) ? (isv ? v1 : q1)
                                 : (isv ? v2 : q2);
        #pragma unroll
        for (int cf = 0; cf < 4; ++cf) {
            f16x4 hv;
            hv[0] = (_Float16)(acc[rf][cf][0] + bi.x);
            hv[1] = (_Float16)(acc[rf][cf][1] + bi.y);
            hv[2] = (_Float16)(acc[rf][cf][2] + bi.z);
            hv[3] = (_Float16)(acc[rf][cf][3] + bi.w);
            *reinterpret_cast<f16x4*>(tb + (size_t)ro[sc][cf]*32 + c32) = hv;
        }
    }
#undef CLOAD
#undef CWRITE
#undef CCOMP
}

// ---- Flash attention body: r10 online softmax, per-rb fused P+PV ----------
// Pw per wave = [16 q rows][40 f16] (1.28KB) — rb iterations reuse it (wave
// DS ops are in-order; no barrier needed).
template<int GROUP>
__device__ __forceinline__ void attn_body(
    int bid, uint4* Kl, _Float16* Vt, _Float16* Pl,
    const _Float16* __restrict__ Q, const _Float16* __restrict__ Ks,
    const _Float16* Vs, _Float16* O)
{
    constexpr int S   = (GROUP==0) ? 16 : (GROUP==1) ? 64 : 256;
    constexpr int GB  = 256 / S;
    constexpr int KT  = (S < 32) ? 16 : 32;
    constexpr int NT  = S / KT;
    constexpr int CBS = KT / 16;

    const int t = threadIdx.x;
    {
        const int g = t / S, j = t % S;
        const int bq = bid * GB + g;
        int krow, vrow;
        if constexpr (GROUP == 0) {
            krow = (bq >> 2)*64  + (j << 2) + (bq & 3);
            vrow = (bq >> 4)*256 + (j << 4) + (bq & 15);
        } else if constexpr (GROUP == 1) {
            krow = (bq >> 2)*256 + (j << 2) + (bq & 3);
            vrow = ((bq << 2) + (j & 3))*16 + (j >> 2);
        } else {
            krow = ((bq << 4) + (j & 15))*16 + (j >> 4);
            vrow = ((bq << 2) + (j & 3))*64 + (j >> 2);
        }
        const uint4* ks = reinterpret_cast<const uint4*>(Ks + (size_t)krow*32);
        uint4 ka = ks[0], kb = ks[1], kc = ks[2], kd = ks[3];
        Kl[0*256 + t] = ka; Kl[1*256 + t] = kb;
        Kl[2*256 + t] = kc; Kl[3*256 + t] = kd;
        union { uint4 u4[4]; _Float16 h[32]; } vb;
        const uint4* vs = reinterpret_cast<const uint4*>(Vs + (size_t)vrow*32);
        vb.u4[0] = vs[0]; vb.u4[1] = vs[1]; vb.u4[2] = vs[2]; vb.u4[3] = vs[3];
        #pragma unroll
        for (int d = 0; d < 32; ++d) Vt[d*264 + t] = vb.h[d];
        Vt[(t >> 3)*264 + 256 + (t & 7)] = (_Float16)0.f;
        if (t < 8) Vt[32*264 + t] = (_Float16)0.f;
    }
    const int wv = t >> 6, ln = t & 63;
    const int lo = ln & 15, hi = ln >> 4;
    _Float16* Pw = Pl + wv*(16*40);
    if constexpr (S == 16) {   // zero cols 16..31 (dwords 8..15) of 16 rows
        uint* pw32 = reinterpret_cast<uint*>(Pw);
        pw32[(ln >> 2)*20 +  8 + (ln & 3)] = 0u;
        pw32[(ln >> 2)*20 + 12 + (ln & 3)] = 0u;
    }
    __syncthreads();

    const int rowbase = bid*256 + wv*64;
    f16x8 qf[4];
    #pragma unroll
    for (int rb = 0; rb < 4; ++rb) {
        uint4 qv = *reinterpret_cast<const uint4*>(
            Q + ((size_t)(rowbase + rb*16 + lo))*32 + hi*8);
        qf[rb] = __builtin_bit_cast(f16x8, qv);
    }

    f32x4 ofr[4][2];
    float m[4], ls[4];
    #pragma unroll
    for (int rb = 0; rb < 4; ++rb) {
        m[rb] = -1e30f; ls[rb] = 0.f;
        ofr[rb][0] = f32x4{0.f,0.f,0.f,0.f};
        ofr[rb][1] = f32x4{0.f,0.f,0.f,0.f};
    }
    const f32x4 zf = f32x4{0.f,0.f,0.f,0.f};

    for (int tt = 0; tt < NT; ++tt) {
        f16x8 bk[CBS];
        if constexpr (S != 16) {
            const int wb = (S == 64) ? wv*64 : 0;
            #pragma unroll
            for (int cb = 0; cb < CBS; ++cb) {
                int key = wb + tt*KT + cb*16 + lo;
                bk[cb] = __builtin_bit_cast(f16x8, Kl[hi*256 + key]);
            }
        }

        #pragma unroll
        for (int rb = 0; rb < 4; ++rb) {
            f32x4 sf[CBS];
            if constexpr (S == 16) {
                int key = wv*64 + rb*16 + lo;
                f16x8 bk0 = __builtin_bit_cast(f16x8, Kl[hi*256 + key]);
                sf[0] = __builtin_amdgcn_mfma_f32_16x16x32_f16(bk0, qf[rb], zf, 0,0,0);
            } else {
                #pragma unroll
                for (int cb = 0; cb < CBS; ++cb)
                    sf[cb] = __builtin_amdgcn_mfma_f32_16x16x32_f16(bk[cb], qf[rb], zf, 0,0,0);
            }

            float tm = sf[0][0];
            #pragma unroll
            for (int cb = 0; cb < CBS; ++cb)
                #pragma unroll
                for (int r = 0; r < 4; ++r)
                    if (cb | r) tm = fmaxf(tm, sf[cb][r]);
            tm = fmaxf(tm, __shfl_xor(tm, 16));
            tm = fmaxf(tm, __shfl_xor(tm, 32));
            float mn = fmaxf(m[rb], tm);
            float sc = exp2_fast(m[rb] - mn);
            m[rb] = mn;
            float ps = 0.f;
            #pragma unroll
            for (int cb = 0; cb < CBS; ++cb) {
                float p0 = exp2_fast(sf[cb][0] - mn);
                float p1 = exp2_fast(sf[cb][1] - mn);
                float p2 = exp2_fast(sf[cb][2] - mn);
                float p3 = exp2_fast(sf[cb][3] - mn);
                ps += (p0+p1)+(p2+p3);
                unsigned w01 = pkrtz(p0, p1);
                unsigned w23 = pkrtz(p2, p3);
                _Float16* pp = Pw + lo*40 + cb*16 + hi*4;
                *reinterpret_cast<unsigned*>(pp)     = w01;
                *reinterpret_cast<unsigned*>(pp + 2) = w23;
            }
            ls[rb] = ls[rb]*sc + ps;
            float s0 = __shfl(sc, hi*4 + 0);
            float s1 = __shfl(sc, hi*4 + 1);
            float s2 = __shfl(sc, hi*4 + 2);
            float s3 = __shfl(sc, hi*4 + 3);
            ofr[rb][0][0]*=s0; ofr[rb][0][1]*=s1; ofr[rb][0][2]*=s2; ofr[rb][0][3]*=s3;
            ofr[rb][1][0]*=s0; ofr[rb][1][1]*=s1; ofr[rb][1][2]*=s2; ofr[rb][1][3]*=s3;

            // PV for this rb (Pw rows reused next rb; wave DS ops are in-order)
            f16x8 pa = *reinterpret_cast<const f16x8*>(Pw + lo*40 + hi*8);
            const int wb2 = (S == 16) ? wv*64 + rb*16 : (S == 64) ? wv*64 : 0;
            const int key0 = wb2 + tt*KT + hi*8;
            #pragma unroll
            for (int dcb = 0; dcb < 2; ++dcb) {
                f16x8 bv = *reinterpret_cast<const f16x8*>(Vt + (dcb*16 + lo)*264 + key0);
                ofr[rb][dcb] = __builtin_amdgcn_mfma_f32_16x16x32_f16(pa, bv, ofr[rb][dcb], 0,0,0);
            }
        }
    }

    #pragma unroll
    for (int rb = 0; rb < 4; ++rb) {
        float v = ls[rb];
        v += __shfl_xor(v, 16);
        v += __shfl_xor(v, 32);
        float linv = 1.f / v;
        float l0 = __shfl(linv, hi*4 + 0);
        float l1 = __shfl(linv, hi*4 + 1);
        float l2 = __shfl(linv, hi*4 + 2);
        float l3 = __shfl(linv, hi*4 + 3);
        #pragma unroll
        for (int dcb = 0; dcb < 2; ++dcb) {
            float lr[4] = {l0, l1, l2, l3};
            #pragma unroll
            for (int r = 0; r < 4; ++r) {
                float ov = ofr[rb][dcb][r] * lr[r];
                int row = rowbase + rb*16 + hi*4 + r;
                O[(size_t)row*32 + dcb*16 + lo] = (_Float16)ov;
            }
        }
    }
}

__global__ __launch_bounds__(256) void k_attn_all(
    const _Float16* __restrict__ q0, const _Float16* __restrict__ v0,
    const _Float16* __restrict__ q1, const _Float16* __restrict__ v1,
    const _Float16* __restrict__ q2, const _Float16* __restrict__ v2)
{
    __shared__ __align__(16) char smem[16384 + 16912 + 5120];
    uint4*    Kl = reinterpret_cast<uint4*>(smem);
    _Float16* Vt = reinterpret_cast<_Float16*>(smem + 16384);
    _Float16* Pl = reinterpret_cast<_Float16*>(smem + 16384 + 16912);
    const int bid = (int)blockIdx.x;
    if (bid < 2048)
        attn_body<0>(bid, Kl, Vt, Pl, q0, q1, v2, const_cast<_Float16*>(v2));
    else if (bid < 4096)
        attn_body<1>(bid - 2048, Kl, Vt, Pl, q1, q2, v0, const_cast<_Float16*>(v0));
    else
        attn_body<2>(bid - 4096, Kl, Vt, Pl, q2, q0, v1, const_cast<_Float16*>(v1));
}

// ---- conv_out (r10 verbatim) ----------------------------------------------
__global__ __launch_bounds__(256) void k_conv_out(
    const _Float16* __restrict__ o0, const _Float16* __restrict__ o1,
    const _Float16* __restrict__ o2, const _Float16* __restrict__ wo,
    const float* __restrict__ b_out, float* __restrict__ out)
{
    constexpr int YS = 104;
    __shared__ _Float16 yt[256*YS];
    const int t  = threadIdx.x;
    const int wv = t >> 6, ln = t & 63;
    const int lo = ln & 15, hi = ln >> 4;
    const int bid = (int)blockIdx.x;
    const int swz = (bid & 7)*256 + (bid >> 3);
    const int b = swz >> 8;
    const int h = swz & 255;

    #pragma unroll
    for (int i = 0; i < 3; ++i) {
        const int lg = 2 + i;
        const int ws = 1 << lg;
        const int sft = ws >> 1;
        const int nblk = 256 >> lg;
        int hh = (h - sft) & 255;
        int w  = (t - sft) & 255;
        int nb = (b*nblk + (hh >> lg))*nblk + (w >> lg);
        int roff = nb*(ws*ws) + (hh & (ws-1))*ws + (w & (ws-1));
        const uint4* src = reinterpret_cast<const uint4*>(
            (i==0 ? o0 : i==1 ? o1 : o2) + (size_t)roff*32);
        uint4 r0 = src[0], r1 = src[1], r2 = src[2], r3 = src[3];
        uint4* dst = reinterpret_cast<uint4*>(&yt[t*YS + i*32]);
        dst[0] = r0; dst[1] = r1; dst[2] = r2; dst[3] = r3;
    }

    f16x8 af[6][3];
    #pragma unroll
    for (int rf = 0; rf < 6; ++rf)
        #pragma unroll
        for (int ks = 0; ks < 3; ++ks)
            af[rf][ks] = *reinterpret_cast<const f16x8*>(
                wo + (rf*16 + lo)*96 + ks*32 + hi*8);
    __syncthreads();

    f32x4 acc[6][4];
    #pragma unroll
    for (int rf = 0; rf < 6; ++rf)
        #pragma unroll
        for (int cf = 0; cf < 4; ++cf) acc[rf][cf] = f32x4{0.f,0.f,0.f,0.f};

    #pragma unroll
    for (int cf = 0; cf < 4; ++cf) {
        const int px = wv*64 + cf*16 + lo;
        #pragma unroll
        for (int ks = 0; ks < 3; ++ks) {
            f16x8 bfv = *reinterpret_cast<const f16x8*>(&yt[px*YS + ks*32 + hi*8]);
            #pragma unroll
            for (int rf = 0; rf < 6; ++rf)
                acc[rf][cf] = __builtin_amdgcn_mfma_f32_16x16x32_f16(
                                  af[rf][ks], bfv, acc[rf][cf], 0,0,0);
        }
    }

    const size_t obase = (size_t)b*96*65536 + (size_t)h*256;
    #pragma unroll
    for (int rf = 0; rf < 6; ++rf) {
        const int oo = rf*16 + hi*4;
        float4 bi = *reinterpret_cast<const float4*>(b_out + oo);
        #pragma unroll
        for (int cf = 0; cf < 4; ++cf) {
            const int px = wv*64 + cf*16 + lo;
            out[obase + (size_t)(oo+0)*65536 + px] = acc[rf][cf][0] + bi.x;
            out[obase + (size_t)(oo+1)*65536 + px] = acc[rf][cf][1] + bi.y;
            out[obase + (size_t)(oo+2)*65536 + px] = acc[rf][cf][2] + bi.z;
            out[obase + (size_t)(oo+3)*65536 + px] = acc[rf][cf][3] + bi.w;
        }
    }
}

extern "C" void kernel_launch(void* const* d_in, const int* in_sizes, int n_in,
                              void* d_out, int out_size, void* d_ws, size_t ws_size,
                              hipStream_t stream)
{
    const float* x     = (const float*)d_in[0];
    const float* w_in  = (const float*)d_in[1];
    const float* b_in  = (const float*)d_in[2];
    const float* gma   = (const float*)d_in[3];
    const float* bta   = (const float*)d_in[4];
    const float* mu    = (const float*)d_in[5];
    const float* var   = (const float*)d_in[6];
    const float* w_out = (const float*)d_in[7];
    const float* b_out = (const float*)d_in[8];
    float* out = (float*)d_out;

    _Float16* W = (_Float16*)d_ws;
    const size_t M = 16777216;
    _Float16 *q0 = W,       *v0 = W +   M, *q1 = W + 2*M,
             *v1 = W + 3*M, *q2 = W + 4*M, *v2 = W + 5*M;
    _Float16* wf = W + 6*M;
    float*    bs = (float*)(W + 6*M + 18432);
    _Float16* wo = W + 6*M + 18432 + 384;

    k_prep<<<1, 256, 0, stream>>>(w_in, b_in, gma, bta, mu, var, w_out, wf, bs, wo);
    k_conv_in<<<4096, 256, 0, stream>>>(x, wf, bs, q0, v0, q1, v1, q2, v2);
    k_attn_all<<<6144, 256, 0, stream>>>(q0, v0, q1, v1, q2, v2);
    k_conv_out<<<2048, 256, 0, stream>>>(v2, v0, v1, wo, b_out, out);
}